// Round 12
// baseline (19.295 us; speedup 1.0000x reference)
//
#include <hip/hip_runtime.h>
#include <math.h>

#define DIM    128
#define DIM2   256
#define NSIGN  4
#define CCONST 0.618f
#define MB     16
#define NTHR   512

typedef short bf16x8 __attribute__((ext_vector_type(8)));
typedef float f32x4  __attribute__((ext_vector_type(4)));

#define MFMA(a,b,c) __builtin_amdgcn_mfma_f32_16x16x32_bf16((a),(b),(c),0,0,0)

union BU { uint4 q; bf16x8 b; unsigned short u[8]; };

__device__ __forceinline__ unsigned short f2bf(float f) {
    unsigned u = __float_as_uint(f);
    u += 0x7fffu + ((u >> 16) & 1u);          // round-to-nearest-even
    return (unsigned short)(u >> 16);
}
__device__ __forceinline__ float bf2f(unsigned short h) {
    return __uint_as_float(((unsigned)h) << 16);
}
__device__ __forceinline__ bf16x8 frag16(const unsigned short* p) {
    BU u; u.q = *(const uint4*)p; return u.b;
}
// convert 8 fp32 -> hi plane only
__device__ __forceinline__ bf16x8 cvt_hi(const float* f) {
    BU H;
    #pragma unroll
    for (int e = 0; e < 8; ++e) H.u[e] = f2bf(f[e]);
    return H.b;
}
// convert 8 fp32 -> hi + lo planes (identical math to old prep_pack)
__device__ __forceinline__ void cvt_hl(const float* f, bf16x8& h8, bf16x8& l8) {
    BU H, L;
    #pragma unroll
    for (int e = 0; e < 8; ++e) {
        unsigned short hb = f2bf(f[e]);
        H.u[e] = hb;
        L.u[e] = f2bf(f[e] - bf2f(hb));
    }
    h8 = H.b; l8 = L.b;
}

// ---------------- single fused kernel: no prep, direct native weight loads ----------------
// B-fragment sources (lane: g = lane>>4, c15 = lane&15, e = 0..7):
//   pass1 (W1T): W1[(nt*16+c15)*128 + kt*32+8g+e]  -> 8 consecutive floats (hi+lo)
//   pass2 (W2T): W2[(w *16+c15)*256 + kt*32+8g+e]  -> 8 consecutive floats (hi)
//   pass3 (W2 ): W2[(kt*32+8g+e)*256 + nt*16+c15]  -> 8 gathers, stride 256 (hi)
//   pass4 (W1 ): W1[(kt*32+8g+e)*128 + w*16+c15]   -> 8 gathers, stride 128 (hi)
__global__ __launch_bounds__(NTHR, 1)
void fused_connection(const float* __restrict__ input_,
                      const float* __restrict__ W1,
                      const float* __restrict__ b1,
                      const float* __restrict__ W2,
                      const float* __restrict__ b2,
                      float* __restrict__ out) {
    __shared__ __align__(16) float          vv [MB][132];   // v fp32
    __shared__ __align__(16) unsigned short xbH[MB][136];   // x hi plane
    __shared__ __align__(16) unsigned short xbL[MB][136];   // x lo plane
    __shared__ __align__(16) unsigned short vbH[MB][136];   // v hi plane
    __shared__ __align__(16) unsigned short aH [MB][264];   // a  bf16-hi
    __shared__ __align__(16) unsigned short mwH[MB][264];   // mw hi ; reused as mu hi
    __shared__ __align__(16) unsigned short vcH[MB][136];   // vc hi

    const int t    = threadIdx.x;
    const int lane = t & 63;
    const int w    = t >> 6;             // wave id 0..7
    const int b0   = blockIdx.x * MB;
    const int arow = lane & 15;          // A-frag row / B-col / C-col component
    const int kg   = (lane >> 4) << 3;   // k-offset of this lane group
    const int rbase = (lane >> 4) << 2;  // C/D row base (verified m89 layout)

    // ---- issue the HBM input load FIRST (longest latency) ----
    const int prow = t >> 5;             // 0..15
    const int pc   = (t & 31) * 8;       // 0..248
    const float4* src = (const float4*)(input_ + (size_t)(b0 + prow) * DIM2 + pc);
    const float4 f0 = src[0];
    const float4 f1 = src[1];

    // ---- prefetch pass-1 B floats (2 nt x 4 kt x 8 consecutive) + biases ----
    float p1f[2][4][8];
    #pragma unroll
    for (int nt2 = 0; nt2 < 2; ++nt2)
        #pragma unroll
        for (int kt = 0; kt < 4; ++kt) {
            const float* bp = W1 + (size_t)(((w * 2 + nt2) * 16 + arow) * DIM + kt * 32 + kg);
            const float4 a = *(const float4*)bp;
            const float4 b = *(const float4*)(bp + 4);
            p1f[nt2][kt][0] = a.x; p1f[nt2][kt][1] = a.y; p1f[nt2][kt][2] = a.z; p1f[nt2][kt][3] = a.w;
            p1f[nt2][kt][4] = b.x; p1f[nt2][kt][5] = b.y; p1f[nt2][kt][6] = b.z; p1f[nt2][kt][7] = b.w;
        }
    const float b1v0 = b1[(w * 2 + 0) * 16 + arow];
    const float b1v1 = b1[(w * 2 + 1) * 16 + arow];
    const float b2v  = b2[w * 16 + arow];

    // ---- phase 0: convert in-register, stage planes; v -> out ----
    {
        float fa[8] = {f0.x, f0.y, f0.z, f0.w, f1.x, f1.y, f1.z, f1.w};
        if (pc < DIM) {
            BU H, L;
            #pragma unroll
            for (int e = 0; e < 8; ++e) {
                unsigned short hb = f2bf(fa[e]);
                H.u[e] = hb;
                L.u[e] = f2bf(fa[e] - bf2f(hb));
            }
            *(uint4*)&xbH[prow][pc] = H.q;
            *(uint4*)&xbL[prow][pc] = L.q;
        } else {
            int c = pc - DIM;
            *(float4*)&vv[prow][c]     = f0;
            *(float4*)&vv[prow][c + 4] = f1;
            BU H;
            #pragma unroll
            for (int e = 0; e < 8; ++e) H.u[e] = f2bf(fa[e]);
            *(uint4*)&vbH[prow][c] = H.q;
            // v -> out[:, :128] straight from registers
            float4* op = (float4*)(out + (size_t)(b0 + prow) * DIM2 + c);
            op[0] = f0; op[1] = f1;
        }
    }
    __syncthreads();

    // ---- Pass 1: h = x.W1^T + b1 (3-term split), w = v.W1^T (hi) ----
    float p2f[8][8];
    {
        // prefetch pass-2 B floats (8 kt x 8 consecutive from W2 row w*16+arow)
        #pragma unroll
        for (int kt = 0; kt < 8; ++kt) {
            const float* bp = W2 + (size_t)((w * 16 + arow) * DIM2 + kt * 32 + kg);
            const float4 a = *(const float4*)bp;
            const float4 b = *(const float4*)(bp + 4);
            p2f[kt][0] = a.x; p2f[kt][1] = a.y; p2f[kt][2] = a.z; p2f[kt][3] = a.w;
            p2f[kt][4] = b.x; p2f[kt][5] = b.y; p2f[kt][6] = b.z; p2f[kt][7] = b.w;
        }

        bf16x8 xH[4], xL[4], vH[4];
        #pragma unroll
        for (int kt = 0; kt < 4; ++kt) {
            int k0 = kt * 32 + kg;
            xH[kt] = frag16(&xbH[arow][k0]);
            xL[kt] = frag16(&xbL[arow][k0]);
            vH[kt] = frag16(&vbH[arow][k0]);
        }
        #pragma unroll
        for (int nt2 = 0; nt2 < 2; ++nt2) {
            f32x4 ha = {0.f, 0.f, 0.f, 0.f};
            f32x4 wa = {0.f, 0.f, 0.f, 0.f};
            #pragma unroll
            for (int kt = 0; kt < 4; ++kt) {
                bf16x8 bh, bl;
                cvt_hl(p1f[nt2][kt], bh, bl);
                ha = MFMA(xH[kt], bh, ha);
                ha = MFMA(xH[kt], bl, ha);
                ha = MFMA(xL[kt], bh, ha);
                wa = MFMA(vH[kt], bh, wa);
            }
            int col  = (w * 2 + nt2) * 16 + arow;
            float bias = nt2 ? b1v1 : b1v0;
            #pragma unroll
            for (int reg = 0; reg < 4; ++reg) {
                int row = rbase + reg;
                float hv = ha[reg] + bias;
                bool  mk = hv > 0.f;
                aH[row][col]  = f2bf(mk ? hv : 0.f);
                mwH[row][col] = f2bf(mk ? wa[reg] : 0.f);
            }
        }
    }
    __syncthreads();

    // ---- Pass 2: z = a.W2^T + b2 (-> s), t2 = mw.W2^T ; write vc ----
    float sreg[4];
    f32x4 t2a = {0.f, 0.f, 0.f, 0.f};
    float p3f[2][4][8];
    {
        // prefetch pass-3 B floats (gathers, stride 256)
        #pragma unroll
        for (int nt2 = 0; nt2 < 2; ++nt2)
            #pragma unroll
            for (int kt = 0; kt < 4; ++kt) {
                const float* bp = W2 + (size_t)((kt * 32 + kg) * DIM2 + (w * 2 + nt2) * 16 + arow);
                #pragma unroll
                for (int e = 0; e < 8; ++e)
                    p3f[nt2][kt][e] = bp[e * DIM2];
            }

        f32x4 za = {0.f, 0.f, 0.f, 0.f};
        #pragma unroll
        for (int kt = 0; kt < 8; ++kt) {
            int k0 = kt * 32 + kg;
            bf16x8 af = frag16(&aH[arow][k0]);
            bf16x8 mf = frag16(&mwH[arow][k0]);
            bf16x8 bh = cvt_hi(p2f[kt]);
            za  = MFMA(af, bh, za);
            t2a = MFMA(mf, bh, t2a);
        }
        int   ci   = w * 16 + arow;            // i in [0,128)
        float sg_i = (ci < NSIGN) ? -1.f : 1.f;
        #pragma unroll
        for (int reg = 0; reg < 4; ++reg) {
            int row = rbase + reg;
            float z = za[reg] + b2v;
            float s = 1.f / (1.f + __expf(-z));
            sreg[reg] = s;
            float vvl = vv[row][ci];
            vcH[row][ci] = f2bf(vvl * vvl * sg_i * s * (1.f - s));
        }
    }
    __syncthreads();

    // ---- Pass 3: u = vc.W2 ; write mu = mask*u into mwH ----
    float p4f[8][8];
    {
        // prefetch pass-4 B floats (gathers, stride 128)
        #pragma unroll
        for (int kt = 0; kt < 8; ++kt) {
            const float* bp = W1 + (size_t)((kt * 32 + kg) * DIM + w * 16 + arow);
            #pragma unroll
            for (int e = 0; e < 8; ++e)
                p4f[kt][e] = bp[e * DIM];
        }

        bf16x8 cH[4];
        #pragma unroll
        for (int kt = 0; kt < 4; ++kt)
            cH[kt] = frag16(&vcH[arow][kt * 32 + kg]);
        #pragma unroll
        for (int nt2 = 0; nt2 < 2; ++nt2) {
            f32x4 ua = {0.f, 0.f, 0.f, 0.f};
            #pragma unroll
            for (int kt = 0; kt < 4; ++kt) {
                bf16x8 bh = cvt_hi(p3f[nt2][kt]);
                ua = MFMA(cH[kt], bh, ua);
            }
            int ck = (w * 2 + nt2) * 16 + arow;   // k in [0,256)
            #pragma unroll
            for (int reg = 0; reg < 4; ++reg) {
                int row = rbase + reg;
                bool mk = aH[row][ck] != 0;       // a>0 <=> stored bf16 nonzero
                mwH[row][ck] = f2bf(mk ? ua[reg] : 0.f);
            }
        }
    }
    __syncthreads();

    // ---- Pass 4: t1 = mu.W1 ; epilogue dv ----
    {
        f32x4 t1a = {0.f, 0.f, 0.f, 0.f};
        #pragma unroll
        for (int kt = 0; kt < 8; ++kt) {
            bf16x8 mf = frag16(&mwH[arow][kt * 32 + kg]);
            bf16x8 bh = cvt_hi(p4f[kt]);
            t1a = MFMA(mf, bh, t1a);
        }
        int   cj   = w * 16 + arow;            // same col as pass 2 -> sreg/t2a align
        float sg_j = (cj < NSIGN) ? -1.f : 1.f;
        #pragma unroll
        for (int reg = 0; reg < 4; ++reg) {
            int row = rbase + reg;
            float s  = sreg[reg];
            float cv = sg_j * s * (1.f - s);
            float gi = 1.f / (sg_j * (s + CCONST));
            float vvl = vv[row][cj];
            float dv = fmaf(-gi, t1a[reg], 2.f * vvl * gi * cv * t2a[reg]);
            out[(size_t)(b0 + row) * DIM2 + DIM + cj] = dv;
        }
    }
}

extern "C" void kernel_launch(void* const* d_in, const int* in_sizes, int n_in,
                              void* d_out, int out_size, void* d_ws, size_t ws_size,
                              hipStream_t stream) {
    // inputs: t, input_, W1, b1, W2, b2
    const float* input_ = (const float*)d_in[1];
    const float* W1 = (const float*)d_in[2];
    const float* b1 = (const float*)d_in[3];
    const float* W2 = (const float*)d_in[4];
    const float* b2 = (const float*)d_in[5];
    float* out = (float*)d_out;

    const int batch = in_sizes[1] / DIM2;

    fused_connection<<<batch / MB, NTHR, 0, stream>>>(input_, W1, b1, W2, b2, out);
}